// Round 8
// baseline (1865.765 us; speedup 1.0000x reference)
//
#include <hip/hip_runtime.h>
#include <hip/hip_bf16.h>

// Problem constants: B=64, T=512, I=1024, H=1024 (fp32 in/out).
#define BB_   64
#define TT_   512
#define II_   1024
#define HH_   1024

typedef _Float16 half8  __attribute__((ext_vector_type(8)));
typedef _Float16 half4v __attribute__((ext_vector_type(4)));
typedef float    f32x4  __attribute__((ext_vector_type(4)));

// tanh(x) = 1 - 2/(exp(2x)+1); clamp |x|<=16 (tanh saturates; avoids inf/inf).
// v_exp_f32 + v_rcp_f32: ~6 ops vs ocml tanhf's ~300cy chain. abs err ~1e-7,
// invisible vs the f16 comm rounding (absmax 0.0039, r1/r3/r6).
__device__ __forceinline__ float fast_tanh(float x) {
    float t = fminf(fmaxf(x, -16.f), 16.f);
    float e = __builtin_amdgcn_exp2f(t * 2.885390082f);   // exp(2t)
    return 1.f - 2.f * __builtin_amdgcn_rcpf(e + 1.f);
}

// ---------------------------------------------------------------------------
// Single persistent kernel: xp GEMM fused into the recurrence.
//
// Structure = r6 (best measured: rnn 1212us): 256 WGs x 256 thr = 16 groups
// (4 batches) x 16 WGs (64 cols); wave w stages batch w, owns 16 cols with
// full-K W_hh fragments in regs (wf[4][8], 128 regs).
//
// NEW (this round): the xp input-projection GEMM (previously a separate
// ~330us serial launch) is computed in-kernel, hidden under the poll slack.
// Each wave also holds Wih fragments for its 16 cols (wih_f[4][8], 128 regs
// -- gfx950 unified VGPR/AGPR file; MFMA reads A/B from AGPRs fine). Every
// 4 steps the WG stages x for (4 batches x 4 timesteps) = 16 REAL MFMA
// A-rows into xbuf and runs 32 MFMA/wave -> xp for the next 4 steps, held
// in registers. D layout: lane(q,ro) holds xp[b=q][dt=r][col=ro] == exactly
// this lane's epilogue (bat,col) operand -> no shuffles. hold[dt] is indexed
// only by the statically-unrolled dt (no scratch, rule #20).
// x loads issue BEFORE the poll so their HBM latency hides under it.
// xbuf is single-buffered: read only at dt==0 right after the barrier;
// next write is 3 barriers later -> race-free.
//
// Sync protocol: r1/r6 verbatim (passed 4 rounds). Comm word =
// {tag:16|f16:16}; relaxed agent-scope stores/loads only (LLC coherence
// point). NO sc0 anything (r2/r4 hung; r3 sc0-poll cost +120us; r7
// degree-8 cost +200us -- all retired). Double-buffered by step parity;
// max skew 1 step => slot reuse at distance 2 safe. Poison tag 0xAAAA
// never matches tags 1..512. ws = 512 KB exactly.
// ---------------------------------------------------------------------------
__global__ __launch_bounds__(256, 1) void rnn_steps(const float* __restrict__ x,
                                                    const float* __restrict__ Wih,
                                                    const float* __restrict__ bih,
                                                    const float* __restrict__ Whh,
                                                    const float* __restrict__ bhh,
                                                    const float* __restrict__ h0,
                                                    float* __restrict__ out,
                                                    unsigned* __restrict__ comm) {
    // hbuf[slot][row][col]: rows 0..3 = batches (f16 h), row 4 = zeros (pads
    // MFMA A rows 4..15). Row stride 1032 f16 = 2064 B. 20.6 KB.
    __shared__ alignas(16) _Float16 hbuf[2][5][1032];
    // xbuf[row=b*4+dt][k]: f16 x block for 4 steps. 33 KB. Total 53.7 KB.
    __shared__ alignas(16) _Float16 xbuf[16][1032];

    const int tid  = threadIdx.x;
    const int lane = tid & 63;
    const int w    = tid >> 6;             // wave id: stages batch w, owns 16 cols
    const int g    = blockIdx.x >> 4;      // group 0..15
    const int wg   = blockIdx.x & 15;      // wg within group
    const int b0   = g * 4;
    const int j0   = wg * 64;
    const int ro   = lane & 15, q = lane >> 4;
    const int arow = (ro < 4) ? ro : 4;    // h-GEMM A rows >=4 read the zero row
    const int bat  = lane >> 4;            // epilogue: this lane's batch 0..3
    const int colw = j0 + w * 16 + (lane & 15);  // epilogue: this lane's column

    // Preload W_hh and W_ih B-fragments (full K) for this wave's 16 cols:
    // wf[kq][ks][e] = W[n][k], n = j0+w*16+ro, k = kq*256+ks*32+q*8+e.
    // 128 regs each (compiler places overflow in AGPRs; MFMA reads them).
    half8 wf[4][8], wih_f[4][8];
    {
        const float* wrow = Whh + (size_t)(j0 + w * 16 + ro) * HH_;
        const float* vrow = Wih + (size_t)(j0 + w * 16 + ro) * II_;
        #pragma unroll
        for (int kq = 0; kq < 4; ++kq) {
            #pragma unroll
            for (int ks = 0; ks < 8; ++ks) {
                const int kc = kq * 256 + ks * 32 + q * 8;
                const float4 w0 = *(const float4*)(wrow + kc);
                const float4 w1 = *(const float4*)(wrow + kc + 4);
                half8 hv;
                hv[0] = (_Float16)w0.x; hv[1] = (_Float16)w0.y;
                hv[2] = (_Float16)w0.z; hv[3] = (_Float16)w0.w;
                hv[4] = (_Float16)w1.x; hv[5] = (_Float16)w1.y;
                hv[6] = (_Float16)w1.z; hv[7] = (_Float16)w1.w;
                wf[kq][ks] = hv;
                const float4 u0 = *(const float4*)(vrow + kc);
                const float4 u1 = *(const float4*)(vrow + kc + 4);
                half8 gv;
                gv[0] = (_Float16)u0.x; gv[1] = (_Float16)u0.y;
                gv[2] = (_Float16)u0.z; gv[3] = (_Float16)u0.w;
                gv[4] = (_Float16)u1.x; gv[5] = (_Float16)u1.y;
                gv[6] = (_Float16)u1.z; gv[7] = (_Float16)u1.w;
                wih_f[kq][ks] = gv;
            }
        }
    }
    const float bhh_r = bhh[colw];
    const float bih_r = bih[colw];

    // zero row 4 of both hbuf slots
    for (int i = tid; i < 1032; i += 256) {
        hbuf[0][4][i] = (_Float16)0.f;
        hbuf[1][4][i] = (_Float16)0.f;
    }

    // x staging assignment: thread -> (row = b*4+dt, 64-col segment)
    const int xrow = tid >> 4;             // 0..15
    const int xseg = tid & 15;             // 16 float4 per thread
    const int xb   = xrow >> 2, xdt = xrow & 3;

    const f32x4 zero4 = {0.f, 0.f, 0.f, 0.f};

    #define TAGOK_(v) ((((unsigned)((v) >> 16) & 0xffffu) == su) & \
                       ((unsigned)((v) >> 48) == su))

    f32x4 hold = zero4;   // xp for steps sblk*4 + dt, element dt (static idx)

    for (int sblk = 0; sblk < TT_ / 4; ++sblk) {
        // ---- issue x loads for this 4-step block BEFORE the poll ----
        const float* xsrc = x + ((size_t)(b0 + xb) * TT_ + sblk * 4 + xdt) * II_;
        float4 xl[16];
        #pragma unroll
        for (int i = 0; i < 16; ++i)
            xl[i] = *(const float4*)(xsrc + xseg * 4 + i * 64);

        #pragma unroll
        for (int dt = 0; dt < 4; ++dt) {
            const int s = sblk * 4 + dt;
            const int slot = s & 1;

            // ---- stage h_s into hbuf[slot][w][:] as packed f16 pairs ----
            unsigned* dstw = (unsigned*)(&hbuf[slot][w][0]);
            if (s == 0) {
                const float2* hrow = (const float2*)(h0 + (size_t)(b0 + w) * HH_);
                #pragma unroll
                for (int c = 0; c < 8; ++c) {
                    const float2 hv = hrow[c * 64 + lane];
                    union { _Float16 h[2]; unsigned u; } pk;
                    pk.h[0] = (_Float16)hv.x; pk.h[1] = (_Float16)hv.y;
                    dstw[c * 64 + lane] = pk.u;
                }
            } else {
                const unsigned su = (unsigned)s;
                const unsigned long long* sp = (const unsigned long long*)
                    (comm + (size_t)slot * (BB_ * HH_) + (size_t)(b0 + w) * HH_);
                unsigned long long v0, v1, v2, v3, v4, v5, v6, v7;
                bool ok = false;
                while (!ok) {
                    v0 = __hip_atomic_load(sp + 0 * 64 + lane, __ATOMIC_RELAXED, __HIP_MEMORY_SCOPE_AGENT);
                    v1 = __hip_atomic_load(sp + 1 * 64 + lane, __ATOMIC_RELAXED, __HIP_MEMORY_SCOPE_AGENT);
                    v2 = __hip_atomic_load(sp + 2 * 64 + lane, __ATOMIC_RELAXED, __HIP_MEMORY_SCOPE_AGENT);
                    v3 = __hip_atomic_load(sp + 3 * 64 + lane, __ATOMIC_RELAXED, __HIP_MEMORY_SCOPE_AGENT);
                    v4 = __hip_atomic_load(sp + 4 * 64 + lane, __ATOMIC_RELAXED, __HIP_MEMORY_SCOPE_AGENT);
                    v5 = __hip_atomic_load(sp + 5 * 64 + lane, __ATOMIC_RELAXED, __HIP_MEMORY_SCOPE_AGENT);
                    v6 = __hip_atomic_load(sp + 6 * 64 + lane, __ATOMIC_RELAXED, __HIP_MEMORY_SCOPE_AGENT);
                    v7 = __hip_atomic_load(sp + 7 * 64 + lane, __ATOMIC_RELAXED, __HIP_MEMORY_SCOPE_AGENT);
                    bool o = true;
                    o &= TAGOK_(v0); o &= TAGOK_(v1); o &= TAGOK_(v2); o &= TAGOK_(v3);
                    o &= TAGOK_(v4); o &= TAGOK_(v5); o &= TAGOK_(v6); o &= TAGOK_(v7);
                    ok = o;
                }
                #define PACK_(x) ((unsigned)((x) & 0xffffull) | (((unsigned)((x) >> 32)) << 16))
                dstw[0 * 64 + lane] = PACK_(v0);
                dstw[1 * 64 + lane] = PACK_(v1);
                dstw[2 * 64 + lane] = PACK_(v2);
                dstw[3 * 64 + lane] = PACK_(v3);
                dstw[4 * 64 + lane] = PACK_(v4);
                dstw[5 * 64 + lane] = PACK_(v5);
                dstw[6 * 64 + lane] = PACK_(v6);
                dstw[7 * 64 + lane] = PACK_(v7);
                #undef PACK_
            }

            if (dt == 0) {
                // write the x block (loads issued above have completed under
                // the poll latency): f32x4 -> half4v, stride-1032 rows.
                #pragma unroll
                for (int i = 0; i < 16; ++i) {
                    half4v hx = { (_Float16)xl[i].x, (_Float16)xl[i].y,
                                  (_Float16)xl[i].z, (_Float16)xl[i].w };
                    *(half4v*)(&xbuf[xrow][xseg * 4 + i * 64]) = hx;
                }
            }
            __syncthreads();   // the only barrier per step

            if (dt == 0) {
                // ---- xp MFMA: 16 (b,dt) rows x 16 cols x K=1024 ----
                f32x4 accx[4] = {zero4, zero4, zero4, zero4};
                const _Float16* xbase = &xbuf[0][0] + (size_t)ro * 1032;
                #pragma unroll
                for (int kq = 0; kq < 4; ++kq) {
                    #pragma unroll
                    for (int ks = 0; ks < 8; ++ks) {
                        const half8 a = *(const half8*)(xbase + kq * 256 + ks * 32 + q * 8);
                        accx[kq] = __builtin_amdgcn_mfma_f32_16x16x32_f16(a, wih_f[kq][ks], accx[kq], 0, 0, 0);
                    }
                }
                hold = accx[0] + accx[1] + accx[2] + accx[3];
                hold += (f32x4){bih_r, bih_r, bih_r, bih_r};
            }

            // ---- h MFMA: this wave's 16 cols x full K=1024 ----
            f32x4 acc[4] = {zero4, zero4, zero4, zero4};
            const _Float16* abase = &hbuf[slot][0][0] + (size_t)arow * 1032;
            #pragma unroll
            for (int kq = 0; kq < 4; ++kq) {
                #pragma unroll
                for (int ks = 0; ks < 8; ++ks) {
                    const half8 a = *(const half8*)(abase + kq * 256 + ks * 32 + q * 8);
                    acc[kq] = __builtin_amdgcn_mfma_f32_16x16x32_f16(a, wf[kq][ks], acc[kq], 0, 0, 0);
                }
            }

            // ---- epilogue, all 64 lanes (r3/r6-proven) ----
            const f32x4 sum = acc[0] + acc[1] + acc[2] + acc[3];
            const float t0 = __shfl(sum[0], lane & 15);
            const float t1 = __shfl(sum[1], lane & 15);
            const float t2 = __shfl(sum[2], lane & 15);
            const float t3 = __shfl(sum[3], lane & 15);
            const float val = (bat == 0) ? t0 : (bat == 1) ? t1 : (bat == 2) ? t2 : t3;

            const float hnew = fast_tanh(hold[dt] + bhh_r + val);  // dt static

            // tagged comm word FIRST (inter-WG critical path), out store after.
            union { _Float16 h; unsigned short us; } cv; cv.h = (_Float16)hnew;
            const unsigned word = ((unsigned)(s + 1) << 16) | (unsigned)cv.us;
            __hip_atomic_store(comm + (size_t)((s + 1) & 1) * (BB_ * HH_)
                                    + (size_t)(b0 + bat) * HH_ + colw,
                               word, __ATOMIC_RELAXED, __HIP_MEMORY_SCOPE_AGENT);

            out[((size_t)(b0 + bat) * TT_ + s) * HH_ + colw] = hnew;
            // no trailing barrier: next step stages into hbuf[slot^1]; xbuf
            // rewrite is >=3 barriers after its last read.
        }
    }
    #undef TAGOK_
}

// ---------------------------------------------------------------------------
extern "C" void kernel_launch(void* const* d_in, const int* in_sizes, int n_in,
                              void* d_out, int out_size, void* d_ws, size_t ws_size,
                              hipStream_t stream) {
    (void)in_sizes; (void)n_in; (void)out_size; (void)ws_size;

    const float* x   = (const float*)d_in[0];
    const float* h0  = (const float*)d_in[1];
    const float* Wih = (const float*)d_in[2];
    const float* bih = (const float*)d_in[3];
    const float* Whh = (const float*)d_in[4];
    const float* bhh = (const float*)d_in[5];
    float* out = (float*)d_out;

    // d_ws: comm only -- 2 slots x 64 x 1024 u32 = 512 KB (r1-verified
    // footprint; no memset needed: poison tag 0xAAAA never matches 1..512).
    unsigned* comm = (unsigned*)d_ws;

    rnn_steps<<<256, 256, 0, stream>>>(x, Wih, bih, Whh, bhh, h0, out, comm);
}

// Round 9
// 1461.545 us; speedup vs baseline: 1.2766x; 1.2766x over previous
//
#include <hip/hip_runtime.h>
#include <hip/hip_bf16.h>

// Problem constants: B=64, T=512, I=1024, H=1024 (fp32 in/out).
#define BB_   64
#define TT_   512
#define II_   1024
#define HH_   1024

typedef _Float16 half8  __attribute__((ext_vector_type(8)));
typedef _Float16 half4v __attribute__((ext_vector_type(4)));
typedef float    f32x4  __attribute__((ext_vector_type(4)));

// tanh(x) = 1 - 2/(exp(2x)+1); clamp |x|<=16 (tanh saturates; avoids inf/inf).
// v_exp_f32 + v_rcp_f32: ~6 ops vs ocml tanhf's ~300cy chain. abs err ~1e-7,
// invisible vs the f16 comm rounding (absmax 0.0039, r1/r3/r6).
__device__ __forceinline__ float fast_tanh(float x) {
    float t = fminf(fmaxf(x, -16.f), 16.f);
    float e = __builtin_amdgcn_exp2f(t * 2.885390082f);   // exp(2t)
    return 1.f - 2.f * __builtin_amdgcn_rcpf(e + 1.f);
}

// ---------------------------------------------------------------------------
// Phase 1: xp[b*T+t][j] = x[b,t,:] . W_ih[j,:] + b_ih[j], written to d_out.
// r9 changes vs r6 (structure otherwise identical / proven):
//  - XCD-aware swizzle: the 8 n-blocks sharing one x m-tile now land on ONE
//    XCD (bid%8 == const) -> x tile fetched ~once per XCD L2 instead of 8x.
//  - BK=64 as two 32-wide sub-tiles (same stride-40 LDS layout, proven):
//    halves the __syncthreads count (64 -> 32 per block).
// ---------------------------------------------------------------------------
__global__ __launch_bounds__(256) void gemm_xp(const float* __restrict__ x,
                                               const float* __restrict__ Wih,
                                               const float* __restrict__ bih,
                                               float* __restrict__ out) {
    __shared__ alignas(16) _Float16 As[2][128 * 40];   // [sub-tile][row*40+col]
    __shared__ alignas(16) _Float16 Bs[2][128 * 40];

    const int tid  = threadIdx.x;
    // swizzle: xcd = bid&7 (round-robin heuristic), 8 same-bm blocks per XCD
    const int xcd  = blockIdx.x & 7;
    const int idx  = blockIdx.x >> 3;              // 0..255
    const int bm   = xcd + 8 * (idx >> 3);         // 256 m-tiles, bm%8==xcd
    const int bn   = idx & 7;                      // 8 n-tiles
    const int M0   = bm * 128, N0 = bn * 128;
    const int lane = tid & 63, w = tid >> 6;
    const int wm   = (w & 1) * 64, wn = (w >> 1) * 64;   // wave quadrant
    const int ro   = lane & 15, q = lane >> 4;
    const int sr   = tid >> 3, sc = tid & 7;       // staging: 32 rows x 8 chunks

    const f32x4 zero4 = {0.f, 0.f, 0.f, 0.f};
    f32x4 acc[4][4];
    #pragma unroll
    for (int i = 0; i < 4; ++i)
        #pragma unroll
        for (int j = 0; j < 4; ++j) acc[i][j] = zero4;

    for (int kk = 0; kk < 16; ++kk) {              // BK=64 per iter
        #pragma unroll
        for (int sub = 0; sub < 2; ++sub) {
            const int k0 = kk * 64 + sub * 32;
            #pragma unroll
            for (int ir = 0; ir < 4; ++ir) {
                const int row = ir * 32 + sr;
                const float4 av = *(const float4*)(x   + (size_t)(M0 + row) * II_ + k0 + sc * 4);
                const float4 bv = *(const float4*)(Wih + (size_t)(N0 + row) * II_ + k0 + sc * 4);
                half4v ah = { (_Float16)av.x, (_Float16)av.y, (_Float16)av.z, (_Float16)av.w };
                half4v bh = { (_Float16)bv.x, (_Float16)bv.y, (_Float16)bv.z, (_Float16)bv.w };
                *(half4v*)(As[sub] + row * 40 + sc * 4) = ah;
                *(half4v*)(Bs[sub] + row * 40 + sc * 4) = bh;
            }
        }
        __syncthreads();

        half8 a[2][4], b[2][4];
        #pragma unroll
        for (int sub = 0; sub < 2; ++sub)
            #pragma unroll
            for (int i = 0; i < 4; ++i) {
                a[sub][i] = *(const half8*)(As[sub] + (wm + i * 16 + ro) * 40 + q * 8);
                b[sub][i] = *(const half8*)(Bs[sub] + (wn + i * 16 + ro) * 40 + q * 8);
            }
        #pragma unroll
        for (int sub = 0; sub < 2; ++sub)
            #pragma unroll
            for (int i = 0; i < 4; ++i)
                #pragma unroll
                for (int j = 0; j < 4; ++j)
                    acc[i][j] = __builtin_amdgcn_mfma_f32_16x16x32_f16(a[sub][i], b[sub][j], acc[i][j], 0, 0, 0);
        __syncthreads();
    }

    #pragma unroll
    for (int j = 0; j < 4; ++j) {
        const int col = N0 + wn + j * 16 + ro;
        const float bias = bih[col];
        #pragma unroll
        for (int i = 0; i < 4; ++i) {
            #pragma unroll
            for (int r = 0; r < 4; ++r) {
                const int rowg = M0 + wm + i * 16 + q * 4 + r;
                out[(size_t)rowg * HH_ + col] = acc[i][j][r] + bias;
            }
        }
    }
}

// ---------------------------------------------------------------------------
// Phase 2: persistent recurrence -- r6 VERBATIM (best measured: 1212us rnn)
// except a 3-op XOR/mask tag check (was 6 ops/word).
//
// 256 WGs x 256 thr = 16 groups (4 batches) x 16 WGs (64 cols). Wave w of a
// WG owns 16 cols x full K=1024 (W_hh slice in wf[4][8] = 128 VGPRs); no
// cross-wave reduction; ONE __syncthreads per step (LDS double-buffered).
//
// Sync: tagged-word protocol (passed r1/r3/r6). Comm word = {tag:16|f16:16};
// relaxed agent-scope stores/loads only (coherence point = LLC). NO sc0
// anything (r2/r4 hung; r3's sc0 poll +120us; r7 degree-8 +200us; r8 fusion
// +530us -- all retired). Double-buffered by step parity; max skew 1 step
// (posting H_{t+1} requires having read all of H_t) => slot reuse at
// distance 2 safe. Poison tag 0xAAAA never matches tags 1..512. ws = 512 KB.
// ---------------------------------------------------------------------------
__global__ __launch_bounds__(256, 1) void rnn_steps(const float* __restrict__ Whh,
                                                    const float* __restrict__ bhh,
                                                    const float* __restrict__ h0,
                                                    float* __restrict__ out,
                                                    unsigned* __restrict__ comm) {
    // [slot][row][col]: rows 0..3 = batches (f16 h), row 4 = zeros (pads MFMA
    // A rows 4..15). Row stride 1032 f16 = 2064 B.
    __shared__ alignas(16) _Float16 hbuf[2][5][1032];

    const int tid  = threadIdx.x;
    const int lane = tid & 63;
    const int w    = tid >> 6;             // wave id: stages batch w, owns 16 cols
    const int g    = blockIdx.x >> 4;      // group 0..15
    const int wg   = blockIdx.x & 15;      // wg within group
    const int b0   = g * 4;
    const int j0   = wg * 64;
    const int ro   = lane & 15, q = lane >> 4;
    const int arow = (ro < 4) ? ro : 4;    // A rows >=4 read the shared zero row
    const int bat  = lane >> 4;            // epilogue: this lane's batch 0..3
    const int colw = j0 + w * 16 + (lane & 15);  // epilogue: this lane's column

    // Preload W_hh B-fragments (full K): wf[kq][ks][e] = Whh[n][k],
    // n = j0 + w*16 + ro, k = kq*256 + ks*32 + q*8 + e. 128 VGPRs.
    half8 wf[4][8];
    {
        const float* wrow = Whh + (size_t)(j0 + w * 16 + ro) * HH_;
        #pragma unroll
        for (int kq = 0; kq < 4; ++kq) {
            #pragma unroll
            for (int ks = 0; ks < 8; ++ks) {
                const int kc = kq * 256 + ks * 32 + q * 8;
                const float4 w0 = *(const float4*)(wrow + kc);
                const float4 w1 = *(const float4*)(wrow + kc + 4);
                half8 hv;
                hv[0] = (_Float16)w0.x; hv[1] = (_Float16)w0.y;
                hv[2] = (_Float16)w0.z; hv[3] = (_Float16)w0.w;
                hv[4] = (_Float16)w1.x; hv[5] = (_Float16)w1.y;
                hv[6] = (_Float16)w1.z; hv[7] = (_Float16)w1.w;
                wf[kq][ks] = hv;
            }
        }
    }
    const float bhh_r = bhh[colw];

    // zero row 4 of both LDS slots
    for (int i = tid; i < 1032; i += 256) {
        hbuf[0][4][i] = (_Float16)0.f;
        hbuf[1][4][i] = (_Float16)0.f;
    }

    const f32x4 zero4 = {0.f, 0.f, 0.f, 0.f};

    // tag check: word = {tag:16|payload:16} x2 per u64. 3 ops/u64.
    #define TAGMSK_ 0xFFFF0000FFFF0000ull
    #define TAGOK_(v) ((((v) ^ pat) & TAGMSK_) == 0)

    for (int s = 0; s < TT_; ++s) {
        const int slot = s & 1;

        // xp prefetch: one value per lane (batch bat, col colw); issued first
        // so its latency hides under the poll.
        const float xpv = out[((size_t)(b0 + bat) * TT_ + s) * HH_ + colw];

        // ---- stage h_s into hbuf[slot][w][:] as packed f16 pairs ----
        unsigned* dstw = (unsigned*)(&hbuf[slot][w][0]);
        if (s == 0) {
            const float2* hrow = (const float2*)(h0 + (size_t)(b0 + w) * HH_);
            #pragma unroll
            for (int c = 0; c < 8; ++c) {
                const float2 hv = hrow[c * 64 + lane];
                union { _Float16 h[2]; unsigned u; } pk;
                pk.h[0] = (_Float16)hv.x; pk.h[1] = (_Float16)hv.y;
                dstw[c * 64 + lane] = pk.u;
            }
        } else {
            // poll own batch row (8 u64 per lane = 4KB per wave); each 32-bit
            // half carries its own tag => tearing harmless.
            const unsigned long long pat =
                ((unsigned long long)(unsigned)s << 48) |
                ((unsigned long long)(unsigned)s << 16);
            const unsigned long long* sp = (const unsigned long long*)
                (comm + (size_t)slot * (BB_ * HH_) + (size_t)(b0 + w) * HH_);
            unsigned long long v0, v1, v2, v3, v4, v5, v6, v7;
            bool ok = false;
            while (!ok) {
                v0 = __hip_atomic_load(sp + 0 * 64 + lane, __ATOMIC_RELAXED, __HIP_MEMORY_SCOPE_AGENT);
                v1 = __hip_atomic_load(sp + 1 * 64 + lane, __ATOMIC_RELAXED, __HIP_MEMORY_SCOPE_AGENT);
                v2 = __hip_atomic_load(sp + 2 * 64 + lane, __ATOMIC_RELAXED, __HIP_MEMORY_SCOPE_AGENT);
                v3 = __hip_atomic_load(sp + 3 * 64 + lane, __ATOMIC_RELAXED, __HIP_MEMORY_SCOPE_AGENT);
                v4 = __hip_atomic_load(sp + 4 * 64 + lane, __ATOMIC_RELAXED, __HIP_MEMORY_SCOPE_AGENT);
                v5 = __hip_atomic_load(sp + 5 * 64 + lane, __ATOMIC_RELAXED, __HIP_MEMORY_SCOPE_AGENT);
                v6 = __hip_atomic_load(sp + 6 * 64 + lane, __ATOMIC_RELAXED, __HIP_MEMORY_SCOPE_AGENT);
                v7 = __hip_atomic_load(sp + 7 * 64 + lane, __ATOMIC_RELAXED, __HIP_MEMORY_SCOPE_AGENT);
                bool o = true;
                o &= TAGOK_(v0); o &= TAGOK_(v1); o &= TAGOK_(v2); o &= TAGOK_(v3);
                o &= TAGOK_(v4); o &= TAGOK_(v5); o &= TAGOK_(v6); o &= TAGOK_(v7);
                ok = o;
            }
            // pack two f16 halves -> one b32 LDS write (stride-4B, conflict-free)
            #define PACK_(x) ((unsigned)((x) & 0xffffull) | (((unsigned)((x) >> 32)) << 16))
            dstw[0 * 64 + lane] = PACK_(v0);
            dstw[1 * 64 + lane] = PACK_(v1);
            dstw[2 * 64 + lane] = PACK_(v2);
            dstw[3 * 64 + lane] = PACK_(v3);
            dstw[4 * 64 + lane] = PACK_(v4);
            dstw[5 * 64 + lane] = PACK_(v5);
            dstw[6 * 64 + lane] = PACK_(v6);
            dstw[7 * 64 + lane] = PACK_(v7);
            #undef PACK_
        }
        __syncthreads();   // the only barrier per step (LDS double-buffered)

        // ---- MFMA: this wave's 16 cols x full K=1024, 4 independent chains
        f32x4 acc[4] = {zero4, zero4, zero4, zero4};
        const _Float16* abase = &hbuf[slot][0][0] + (size_t)arow * 1032;
        #pragma unroll
        for (int kq = 0; kq < 4; ++kq) {
            #pragma unroll
            for (int ks = 0; ks < 8; ++ks) {
                const half8 a = *(const half8*)(abase + kq * 256 + ks * 32 + q * 8);
                acc[kq] = __builtin_amdgcn_mfma_f32_16x16x32_f16(a, wf[kq][ks], acc[kq], 0, 0, 0);
            }
        }

        // ---- epilogue, all 64 lanes (r3/r6-proven): redistribute D (row =
        // batch on q==0 lanes, col = lane&15) so each lane owns one
        // (batch, col) value -> 1 tanh + 2 stores per lane.
        const f32x4 sum = acc[0] + acc[1] + acc[2] + acc[3];
        const float t0 = __shfl(sum[0], lane & 15);
        const float t1 = __shfl(sum[1], lane & 15);
        const float t2 = __shfl(sum[2], lane & 15);
        const float t3 = __shfl(sum[3], lane & 15);
        const float val = (bat == 0) ? t0 : (bat == 1) ? t1 : (bat == 2) ? t2 : t3;

        const float hnew = fast_tanh(xpv + bhh_r + val);

        // tagged comm word FIRST (inter-WG critical path), out store after.
        union { _Float16 h; unsigned short us; } cv; cv.h = (_Float16)hnew;
        const unsigned word = ((unsigned)(s + 1) << 16) | (unsigned)cv.us;
        __hip_atomic_store(comm + (size_t)((s + 1) & 1) * (BB_ * HH_)
                                + (size_t)(b0 + bat) * HH_ + colw,
                           word, __ATOMIC_RELAXED, __HIP_MEMORY_SCOPE_AGENT);

        out[((size_t)(b0 + bat) * TT_ + s) * HH_ + colw] = hnew;
        // no trailing barrier: next step stages into hbuf[slot^1]; reuse at
        // distance 2 is ordered by the step s+1 __syncthreads.
    }
    #undef TAGOK_
    #undef TAGMSK_
}

// ---------------------------------------------------------------------------
extern "C" void kernel_launch(void* const* d_in, const int* in_sizes, int n_in,
                              void* d_out, int out_size, void* d_ws, size_t ws_size,
                              hipStream_t stream) {
    (void)in_sizes; (void)n_in; (void)out_size; (void)ws_size;

    const float* x   = (const float*)d_in[0];
    const float* h0  = (const float*)d_in[1];
    const float* Wih = (const float*)d_in[2];
    const float* bih = (const float*)d_in[3];
    const float* Whh = (const float*)d_in[4];
    const float* bhh = (const float*)d_in[5];
    float* out = (float*)d_out;

    // d_ws: comm only -- 2 slots x 64 x 1024 u32 = 512 KB (r1-verified
    // footprint; no memset needed: poison tag 0xAAAA never matches 1..512).
    unsigned* comm = (unsigned*)d_ws;

    gemm_xp<<<2048, 256, 0, stream>>>(x, Wih, bih, out);
    rnn_steps<<<256, 256, 0, stream>>>(Whh, bhh, h0, out, comm);
}